// Round 1
// baseline (318.028 us; speedup 1.0000x reference)
//
#include <hip/hip_runtime.h>
#include <math.h>

#define BB 16
#define NN 25200
#define NCLS 80
#define TOPK 1000
#define MAXDET 100
#define TIE_CAP 2048
#define CAND_CAP 1024
static constexpr float NEGV = -1000000000.0f;
static constexpr float IMGSZ = 640.0f;

struct Meta {
  unsigned b1;
  unsigned c_gt;
  unsigned K;
  unsigned ties_needed;
  unsigned cnt;
  unsigned tie_cnt;
  unsigned n_cand;
  unsigned pad;
};

__device__ __forceinline__ unsigned flipKey(float f) {
  unsigned u = __float_as_uint(f);
  return (u & 0x80000000u) ? ~u : (u | 0x80000000u);
}
__device__ __forceinline__ float unflipKey(unsigned k) {
  unsigned u = (k & 0x80000000u) ? (k & 0x7FFFFFFFu) : ~k;
  return __uint_as_float(u);
}

// ---------------- phase 1: scores + high-16 histogram ----------------
__global__ void k_score(const float* __restrict__ regs, const float* __restrict__ clses,
                        unsigned* __restrict__ keys, float* __restrict__ ccs,
                        int* __restrict__ preds, unsigned* __restrict__ hist1) {
  int g = blockIdx.x * blockDim.x + threadIdx.x;
  if (g >= BB * NN) return;
  const float4* row = reinterpret_cast<const float4*>(clses + (size_t)g * NCLS);
  float best = -1.0f;
  int bi = 0;
#pragma unroll
  for (int k = 0; k < NCLS / 4; ++k) {
    float4 v = row[k];
    if (v.x > best) { best = v.x; bi = 4 * k + 0; }
    if (v.y > best) { best = v.y; bi = 4 * k + 1; }
    if (v.z > best) { best = v.z; bi = 4 * k + 2; }
    if (v.w > best) { best = v.w; bi = 4 * k + 3; }
  }
  float pobj = regs[(size_t)g * 5 + 4];
  float sc = pobj * best;
  float s = (sc >= 0.05f) ? sc : NEGV;
  unsigned key = flipKey(s);
  keys[g] = key;
  ccs[g] = best;
  preds[g] = bi;
  int img = g / NN;
  atomicAdd(&hist1[(size_t)img * 65536 + (key >> 16)], 1u);
}

// ---------------- histogram scan (shared for both levels) ----------------
__global__ void k_scan(const unsigned* __restrict__ hist, Meta* __restrict__ meta, int phase) {
  __shared__ unsigned part[256];
  __shared__ unsigned bins[256];
  __shared__ int s_chunk;
  __shared__ unsigned s_cum;
  int img = blockIdx.x;
  int t = threadIdx.x;
  const unsigned* h = hist + (size_t)img * 65536;
  unsigned cgt_prev = meta[img].c_gt;
  unsigned target = (phase == 1) ? (unsigned)TOPK : ((unsigned)TOPK - cgt_prev);
  unsigned s = 0;
  const uint4* h4 = reinterpret_cast<const uint4*>(h) + (size_t)t * 64;
  for (int j = 0; j < 64; ++j) {
    uint4 v = h4[j];
    s += v.x + v.y + v.z + v.w;
  }
  part[t] = s;
  __syncthreads();
  if (t == 0) {
    unsigned cum = 0;
    int chunk = 0;
    for (int c = 255; c >= 0; --c) {
      unsigned pc = part[c];
      if (cum + pc >= target) { chunk = c; break; }
      cum += pc;
    }
    s_chunk = chunk;
    s_cum = cum;
  }
  __syncthreads();
  int chunk = s_chunk;
  bins[t] = h[chunk * 256 + t];
  __syncthreads();
  if (t == 0) {
    unsigned cum = s_cum;
    int bsel = chunk * 256;
    for (int b2 = 255; b2 >= 0; --b2) {
      unsigned hv = bins[b2];
      if (cum + hv >= target) { bsel = chunk * 256 + b2; break; }
      cum += hv;
    }
    if (phase == 1) {
      meta[img].b1 = (unsigned)bsel;
      meta[img].c_gt = cum;
    } else {
      meta[img].K = (meta[img].b1 << 16) | (unsigned)bsel;
      meta[img].ties_needed = (unsigned)TOPK - (cgt_prev + cum);
    }
  }
}

// ---------------- phase 2: low-16 histogram of cutoff bin ----------------
__global__ void k_hist2(const unsigned* __restrict__ keys, const Meta* __restrict__ meta,
                        unsigned* __restrict__ hist2) {
  int g = blockIdx.x * blockDim.x + threadIdx.x;
  if (g >= BB * NN) return;
  int img = g / NN;
  unsigned key = keys[g];
  if ((key >> 16) == meta[img].b1)
    atomicAdd(&hist2[(size_t)img * 65536 + (key & 0xFFFFu)], 1u);
}

// ---------------- decode + candidate write ----------------
__device__ __forceinline__ void decode_write(int img, unsigned pos, int i,
                                             const float* __restrict__ regs,
                                             const float* __restrict__ anchors,
                                             float score, float cc, int pred,
                                             float* __restrict__ cand) {
  const size_t S = (size_t)BB * CAND_CAP;
  size_t g = (size_t)img * NN + (size_t)i;
  const float* r = regs + g * 5;
  float d0 = r[0], d1 = r[1], d2 = r[2], d3 = r[3], obj = r[4];
  const float* a = anchors + (size_t)i * 4;
  float ax1 = a[0], ay1 = a[1], ax2 = a[2], ay2 = a[3];
  float aw = ax2 - ax1, ah = ay2 - ay1;
  float acx = (ax1 + ax2) * 0.5f, acy = (ay1 + ay2) * 0.5f;
  float cx = acx + d0 * aw, cy = acy + d1 * ah;
  float w = aw * expf(d2), h = ah * expf(d3);
  float hw = 0.5f * w, hh = 0.5f * h;
  float x1 = fminf(fmaxf(cx - hw, 0.0f), IMGSZ);
  float y1 = fminf(fmaxf(cy - hh, 0.0f), IMGSZ);
  float x2 = fminf(fmaxf(cx + hw, 0.0f), IMGSZ);
  float y2 = fminf(fmaxf(cy + hh, 0.0f), IMGSZ);
  size_t o = (size_t)img * CAND_CAP + pos;
  cand[0 * S + o] = x1;
  cand[1 * S + o] = y1;
  cand[2 * S + o] = x2;
  cand[3 * S + o] = y2;
  cand[4 * S + o] = obj;
  cand[5 * S + o] = cc;
  cand[6 * S + o] = (float)pred;
  cand[7 * S + o] = score;
  reinterpret_cast<unsigned*>(cand + 8 * S)[o] = (unsigned)i;
}

// ---------------- compaction ----------------
__global__ void k_compact(const float* __restrict__ regs, const float* __restrict__ anchors,
                          const unsigned* __restrict__ keys, const float* __restrict__ ccs,
                          const int* __restrict__ preds, Meta* __restrict__ meta,
                          float* __restrict__ cand, unsigned* __restrict__ ties) {
  int g = blockIdx.x * blockDim.x + threadIdx.x;
  if (g >= BB * NN) return;
  int img = g / NN;
  int i = g - img * NN;
  unsigned key = keys[g];
  unsigned K = meta[img].K;
  if (key > K) {
    unsigned pos = atomicAdd(&meta[img].cnt, 1u);
    if (pos < CAND_CAP)
      decode_write(img, pos, i, regs, anchors, unflipKey(key), ccs[g], preds[g], cand);
  } else if (key == K) {
    unsigned tp = atomicAdd(&meta[img].tie_cnt, 1u);
    if (tp < TIE_CAP) ties[(size_t)img * TIE_CAP + tp] = (unsigned)i;
  }
}

// ---------------- tie resolution (smallest anchor indices first) ----------------
__global__ void k_ties(const float* __restrict__ regs, const float* __restrict__ anchors,
                       const float* __restrict__ ccs, const int* __restrict__ preds,
                       Meta* __restrict__ meta, const unsigned* __restrict__ ties,
                       float* __restrict__ cand) {
  __shared__ unsigned red[256];
  int img = blockIdx.x;
  int t = threadIdx.x;
  unsigned cnt = meta[img].cnt;
  unsigned need = meta[img].ties_needed;
  unsigned nt = meta[img].tie_cnt;
  if (nt > TIE_CAP) nt = TIE_CAP;
  if (need > nt) need = nt;
  float scK = unflipKey(meta[img].K);
  int prev = -1;
  for (unsigned j = 0; j < need; ++j) {
    unsigned local = 0xFFFFFFFFu;
    for (unsigned p = t; p < nt; p += 256) {
      unsigned v = ties[(size_t)img * TIE_CAP + p];
      if ((int)v > prev && v < local) local = v;
    }
    red[t] = local;
    __syncthreads();
    for (int o = 128; o > 0; o >>= 1) {
      if (t < o) {
        unsigned a = red[t + o];
        if (a < red[t]) red[t] = a;
      }
      __syncthreads();
    }
    unsigned m = red[0];
    __syncthreads();
    if (t == 0) {
      decode_write(img, cnt + j, (int)m, regs, anchors, scK, ccs[(size_t)img * NN + m],
                   preds[(size_t)img * NN + m], cand);
    }
    prev = (int)m;
  }
  if (t == 0) meta[img].n_cand = cnt + need;
}

// ---------------- NMS: one block per image, candidates in registers ----------------
__global__ void __launch_bounds__(1024) k_nms(const float* __restrict__ cand,
                                              const Meta* __restrict__ meta,
                                              float* __restrict__ out) {
  const size_t S = (size_t)BB * CAND_CAP;
  int img = blockIdx.x;
  int t = threadIdx.x;
  int n = (int)meta[img].n_cand;
  size_t o = (size_t)img * CAND_CAP + (size_t)t;
  float x1 = 0.f, y1 = 0.f, x2 = 0.f, y2 = 0.f, obj = 0.f, cc = 0.f, cp = 0.f, sc = NEGV;
  unsigned ai = 0xFFFFFFFFu;
  if (t < n) {
    x1 = cand[0 * S + o];
    y1 = cand[1 * S + o];
    x2 = cand[2 * S + o];
    y2 = cand[3 * S + o];
    obj = cand[4 * S + o];
    cc = cand[5 * S + o];
    cp = cand[6 * S + o];
    sc = cand[7 * S + o];
    ai = reinterpret_cast<const unsigned*>(cand + 8 * S)[o];
  }
  float offv = cp * 4096.0f;
  float ox1 = x1 + offv, oy1 = y1 + offv, ox2 = x2 + offv, oy2 = y2 + offv;
  __shared__ unsigned long long s_wave[16];
  __shared__ unsigned long long s_bkey;
  __shared__ float s_best[4];
  for (int it = 0; it < MAXDET; ++it) {
    unsigned long long mykey =
        ((unsigned long long)flipKey(sc) << 32) | (unsigned long long)(0xFFFFFFFFu - ai);
    unsigned long long k = mykey;
#pragma unroll
    for (int o2 = 32; o2 > 0; o2 >>= 1) {
      unsigned long long other = __shfl_xor(k, o2);
      if (other > k) k = other;
    }
    if ((t & 63) == 0) s_wave[t >> 6] = k;
    __syncthreads();
    if (t < 16) {
      unsigned long long k2 = s_wave[t];
#pragma unroll
      for (int o2 = 8; o2 > 0; o2 >>= 1) {
        unsigned long long other = __shfl_xor(k2, o2);
        if (other > k2) k2 = other;
      }
      if (t == 0) s_bkey = k2;
    }
    __syncthreads();
    if (mykey == s_bkey) {
      s_best[0] = ox1;
      s_best[1] = oy1;
      s_best[2] = ox2;
      s_best[3] = oy2;
      float* orow = out + ((size_t)img * MAXDET + it) * 7;
      bool valid = sc > NEGV * 0.5f;
      orow[0] = valid ? x1 : 0.f;
      orow[1] = valid ? y1 : 0.f;
      orow[2] = valid ? x2 : 0.f;
      orow[3] = valid ? y2 : 0.f;
      orow[4] = valid ? obj : 0.f;
      orow[5] = valid ? cc : 0.f;
      orow[6] = valid ? cp : 0.f;
      sc = NEGV;
    }
    __syncthreads();
    float bx1 = s_best[0], by1 = s_best[1], bx2 = s_best[2], by2 = s_best[3];
    float lx = fmaxf(bx1, ox1), ly = fmaxf(by1, oy1);
    float rx = fminf(bx2, ox2), ry = fminf(by2, oy2);
    float iw = fmaxf(rx - lx, 0.f), ih = fmaxf(ry - ly, 0.f);
    float inter = iw * ih;
    float ua = (bx2 - bx1) * (by2 - by1) + (ox2 - ox1) * (oy2 - oy1) - inter;
    float iou = (ua > 0.f) ? inter / ua : 0.f;
    if (iou > 0.5f) sc = NEGV;
    __syncthreads();
  }
}

// ---------------- launch ----------------
extern "C" void kernel_launch(void* const* d_in, const int* in_sizes, int n_in,
                              void* d_out, int out_size, void* d_ws, size_t ws_size,
                              hipStream_t stream) {
  const float* regs = (const float*)d_in[0];
  const float* clses = (const float*)d_in[1];
  const float* anchors = (const float*)d_in[2];
  float* out = (float*)d_out;
  char* ws = (char*)d_ws;

  constexpr size_t HIST_BYTES = (size_t)BB * 65536 * 4;          // 4 MiB each
  constexpr size_t META_OFF = 2 * HIST_BYTES;                    // 8388608
  constexpr size_t META_BYTES = 1024;
  constexpr size_t KEYS_OFF = META_OFF + META_BYTES;             // 8389632
  constexpr size_t ARR_BYTES = (size_t)BB * NN * 4;              // 1612800
  constexpr size_t CCS_OFF = KEYS_OFF + ARR_BYTES;
  constexpr size_t PREDS_OFF = CCS_OFF + ARR_BYTES;
  constexpr size_t CAND_OFF = PREDS_OFF + ARR_BYTES;
  constexpr size_t CAND_BYTES = (size_t)10 * BB * CAND_CAP * 4;  // 655360
  constexpr size_t TIES_OFF = CAND_OFF + CAND_BYTES;

  unsigned* hist1 = (unsigned*)(ws);
  unsigned* hist2 = (unsigned*)(ws + HIST_BYTES);
  Meta* meta = (Meta*)(ws + META_OFF);
  unsigned* keys = (unsigned*)(ws + KEYS_OFF);
  float* ccs = (float*)(ws + CCS_OFF);
  int* preds = (int*)(ws + PREDS_OFF);
  float* cand = (float*)(ws + CAND_OFF);
  unsigned* ties = (unsigned*)(ws + TIES_OFF);

  // zero hist1 + hist2 + meta (must happen every launch; ws is not re-poisoned)
  hipMemsetAsync(d_ws, 0, KEYS_OFF, stream);

  int blocks = (BB * NN + 255) / 256;
  k_score<<<blocks, 256, 0, stream>>>(regs, clses, keys, ccs, preds, hist1);
  k_scan<<<BB, 256, 0, stream>>>(hist1, meta, 1);
  k_hist2<<<blocks, 256, 0, stream>>>(keys, meta, hist2);
  k_scan<<<BB, 256, 0, stream>>>(hist2, meta, 2);
  k_compact<<<blocks, 256, 0, stream>>>(regs, anchors, keys, ccs, preds, meta, cand, ties);
  k_ties<<<BB, 256, 0, stream>>>(regs, anchors, ccs, preds, meta, ties, cand);
  k_nms<<<BB, 1024, 0, stream>>>(cand, meta, out);
}

// Round 2
// 240.049 us; speedup vs baseline: 1.3248x; 1.3248x over previous
//
#include <hip/hip_runtime.h>
#include <math.h>

#define BB 16
#define NN 25200
#define NCLS 80
#define TOPK 1000
#define MAXDET 100
#define TIE_CAP 2048
#define CAND_CAP 1024
static constexpr float NEGV = -1000000000.0f;
static constexpr float IMGSZ = 640.0f;

struct Meta {
  unsigned b1;
  unsigned c_gt;
  unsigned K;
  unsigned ties_needed;
  unsigned cnt;
  unsigned tie_cnt;
  unsigned n_cand;
  unsigned pad;
};

__device__ __forceinline__ unsigned flipKey(float f) {
  unsigned u = __float_as_uint(f);
  return (u & 0x80000000u) ? ~u : (u | 0x80000000u);
}
__device__ __forceinline__ float unflipKey(unsigned k) {
  unsigned u = (k & 0x80000000u) ? (k & 0x7FFFFFFFu) : ~k;
  return __uint_as_float(u);
}

// ---------------- phase 1: scores + high-16 histogram ----------------
__global__ void k_score(const float* __restrict__ regs, const float* __restrict__ clses,
                        unsigned* __restrict__ keys, float* __restrict__ ccs,
                        int* __restrict__ preds, unsigned* __restrict__ hist1) {
  int g = blockIdx.x * blockDim.x + threadIdx.x;
  if (g >= BB * NN) return;
  const float4* row = reinterpret_cast<const float4*>(clses + (size_t)g * NCLS);
  float best = -1.0f;
  int bi = 0;
#pragma unroll
  for (int k = 0; k < NCLS / 4; ++k) {
    float4 v = row[k];
    if (v.x > best) { best = v.x; bi = 4 * k + 0; }
    if (v.y > best) { best = v.y; bi = 4 * k + 1; }
    if (v.z > best) { best = v.z; bi = 4 * k + 2; }
    if (v.w > best) { best = v.w; bi = 4 * k + 3; }
  }
  float pobj = regs[(size_t)g * 5 + 4];
  float sc = pobj * best;
  float s = (sc >= 0.05f) ? sc : NEGV;
  unsigned key = flipKey(s);
  keys[g] = key;
  ccs[g] = best;
  preds[g] = bi;
  int img = g / NN;
  atomicAdd(&hist1[(size_t)img * 65536 + (key >> 16)], 1u);
}

// ---------------- histogram scan: parallel suffix-scan radix select ----------------
__global__ void __launch_bounds__(256) k_scan(const unsigned* __restrict__ hist,
                                              Meta* __restrict__ meta, int phase) {
  __shared__ unsigned part[256];
  __shared__ unsigned sfx[256];
  __shared__ int s_sel;
  __shared__ unsigned s_cum;
  int img = blockIdx.x;
  int t = threadIdx.x;
  const unsigned* h = hist + (size_t)img * 65536;
  unsigned cgt_prev = (phase == 1) ? 0u : meta[img].c_gt;
  unsigned target = (unsigned)TOPK - cgt_prev;
  // level A: 256 chunk sums
  unsigned s = 0;
  const uint4* h4 = reinterpret_cast<const uint4*>(h) + (size_t)t * 64;
  for (int j = 0; j < 64; ++j) {
    uint4 v = h4[j];
    s += v.x + v.y + v.z + v.w;
  }
  part[t] = s;
  sfx[t] = s;
  __syncthreads();
  for (int d = 1; d < 256; d <<= 1) {
    unsigned v = (t + d < 256) ? sfx[t + d] : 0u;
    __syncthreads();
    sfx[t] += v;
    __syncthreads();
  }
  {
    unsigned incl = sfx[t];
    unsigned excl = incl - part[t];
    if (incl >= target && excl < target) { s_sel = t; s_cum = excl; }
  }
  __syncthreads();
  int chunk = s_sel;
  unsigned cumAbove = s_cum;
  __syncthreads();
  // level B: 256 bins of selected chunk
  unsigned b = h[(size_t)chunk * 256 + t];
  part[t] = b;
  sfx[t] = b;
  __syncthreads();
  for (int d = 1; d < 256; d <<= 1) {
    unsigned v = (t + d < 256) ? sfx[t + d] : 0u;
    __syncthreads();
    sfx[t] += v;
    __syncthreads();
  }
  {
    unsigned incl = cumAbove + sfx[t];
    unsigned excl = incl - part[t];
    if (incl >= target && excl < target) {
      if (phase == 1) {
        meta[img].b1 = (unsigned)(chunk * 256 + t);
        meta[img].c_gt = excl;
      } else {
        meta[img].K = (meta[img].b1 << 16) | (unsigned)(chunk * 256 + t);
        meta[img].ties_needed = target - excl;
      }
    }
  }
}

// ---------------- phase 2: low-16 histogram of cutoff bin ----------------
__global__ void k_hist2(const unsigned* __restrict__ keys, const Meta* __restrict__ meta,
                        unsigned* __restrict__ hist2) {
  int g = blockIdx.x * blockDim.x + threadIdx.x;
  if (g >= BB * NN) return;
  int img = g / NN;
  unsigned key = keys[g];
  if ((key >> 16) == meta[img].b1)
    atomicAdd(&hist2[(size_t)img * 65536 + (key & 0xFFFFu)], 1u);
}

// ---------------- decode + candidate write ----------------
__device__ __forceinline__ void decode_write(int img, unsigned pos, int i,
                                             const float* __restrict__ regs,
                                             const float* __restrict__ anchors,
                                             float score, float cc, int pred,
                                             float* __restrict__ cand) {
  const size_t S = (size_t)BB * CAND_CAP;
  size_t g = (size_t)img * NN + (size_t)i;
  const float* r = regs + g * 5;
  float d0 = r[0], d1 = r[1], d2 = r[2], d3 = r[3], obj = r[4];
  const float* a = anchors + (size_t)i * 4;
  float ax1 = a[0], ay1 = a[1], ax2 = a[2], ay2 = a[3];
  float aw = ax2 - ax1, ah = ay2 - ay1;
  float acx = (ax1 + ax2) * 0.5f, acy = (ay1 + ay2) * 0.5f;
  float cx = acx + d0 * aw, cy = acy + d1 * ah;
  float w = aw * expf(d2), h = ah * expf(d3);
  float hw = 0.5f * w, hh = 0.5f * h;
  float x1 = fminf(fmaxf(cx - hw, 0.0f), IMGSZ);
  float y1 = fminf(fmaxf(cy - hh, 0.0f), IMGSZ);
  float x2 = fminf(fmaxf(cx + hw, 0.0f), IMGSZ);
  float y2 = fminf(fmaxf(cy + hh, 0.0f), IMGSZ);
  size_t o = (size_t)img * CAND_CAP + pos;
  cand[0 * S + o] = x1;
  cand[1 * S + o] = y1;
  cand[2 * S + o] = x2;
  cand[3 * S + o] = y2;
  cand[4 * S + o] = obj;
  cand[5 * S + o] = cc;
  cand[6 * S + o] = (float)pred;
  cand[7 * S + o] = score;
  reinterpret_cast<unsigned*>(cand + 8 * S)[o] = (unsigned)i;
}

// ---------------- compaction ----------------
__global__ void k_compact(const float* __restrict__ regs, const float* __restrict__ anchors,
                          const unsigned* __restrict__ keys, const float* __restrict__ ccs,
                          const int* __restrict__ preds, Meta* __restrict__ meta,
                          float* __restrict__ cand, unsigned* __restrict__ ties) {
  int g = blockIdx.x * blockDim.x + threadIdx.x;
  if (g >= BB * NN) return;
  int img = g / NN;
  int i = g - img * NN;
  unsigned key = keys[g];
  unsigned K = meta[img].K;
  if (key > K) {
    unsigned pos = atomicAdd(&meta[img].cnt, 1u);
    if (pos < CAND_CAP)
      decode_write(img, pos, i, regs, anchors, unflipKey(key), ccs[g], preds[g], cand);
  } else if (key == K) {
    unsigned tp = atomicAdd(&meta[img].tie_cnt, 1u);
    if (tp < TIE_CAP) ties[(size_t)img * TIE_CAP + tp] = (unsigned)i;
  }
}

// ---------------- tie resolution (smallest anchor indices first) ----------------
__global__ void k_ties(const float* __restrict__ regs, const float* __restrict__ anchors,
                       const float* __restrict__ ccs, const int* __restrict__ preds,
                       Meta* __restrict__ meta, const unsigned* __restrict__ ties,
                       float* __restrict__ cand) {
  __shared__ unsigned red[256];
  int img = blockIdx.x;
  int t = threadIdx.x;
  unsigned cnt = meta[img].cnt;
  unsigned need = meta[img].ties_needed;
  unsigned nt = meta[img].tie_cnt;
  if (nt > TIE_CAP) nt = TIE_CAP;
  if (need > nt) need = nt;
  float scK = unflipKey(meta[img].K);
  int prev = -1;
  for (unsigned j = 0; j < need; ++j) {
    unsigned local = 0xFFFFFFFFu;
    for (unsigned p = t; p < nt; p += 256) {
      unsigned v = ties[(size_t)img * TIE_CAP + p];
      if ((int)v > prev && v < local) local = v;
    }
    red[t] = local;
    __syncthreads();
    for (int o = 128; o > 0; o >>= 1) {
      if (t < o) {
        unsigned a = red[t + o];
        if (a < red[t]) red[t] = a;
      }
      __syncthreads();
    }
    unsigned m = red[0];
    __syncthreads();
    if (t == 0) {
      decode_write(img, cnt + j, (int)m, regs, anchors, scK, ccs[(size_t)img * NN + m],
                   preds[(size_t)img * NN + m], cand);
    }
    prev = (int)m;
  }
  if (t == 0) meta[img].n_cand = cnt + need;
}

// ---------------- NMS: one block (4 waves) per image ----------------
// key = flipKey(score)<<25 | (0x7FFF - anchor_idx)<<10 | slot   (slot<1024, ai<32768)
// argmax by key == reference argmax (score desc, anchor idx asc); slot is payload.
__global__ void __launch_bounds__(256) k_nms(const float* __restrict__ cand,
                                             const Meta* __restrict__ meta,
                                             float* __restrict__ out) {
  const size_t S = (size_t)BB * CAND_CAP;
  int img = blockIdx.x;
  int tid = threadIdx.x;
  int lane = tid & 63;
  int wid = tid >> 6;
  int n = (int)meta[img].n_cand;

  __shared__ float lds[CAND_CAP * 8];  // AoS: x1,y1,x2,y2,obj,cc,cp,pad
  __shared__ unsigned long long swave[2][4];

  float x1o[4], y1o[4], x2o[4], y2o[4], area[4];
  unsigned long long key[4];

#pragma unroll
  for (int j = 0; j < 4; ++j) {
    int c = j * 256 + tid;
    size_t o = (size_t)img * CAND_CAP + (size_t)c;
    bool v = c < n;
    float vx1 = cand[0 * S + o], vy1 = cand[1 * S + o];
    float vx2 = cand[2 * S + o], vy2 = cand[3 * S + o];
    float vobj = cand[4 * S + o], vcc = cand[5 * S + o];
    float vcp = cand[6 * S + o], vsc = cand[7 * S + o];
    unsigned vai = reinterpret_cast<const unsigned*>(cand + 8 * S)[o];
    if (!v) { vx1 = vy1 = vx2 = vy2 = 0.f; vobj = vcc = vcp = 0.f; vsc = NEGV; vai = 0x7FFFu; }
    float* L = lds + (size_t)c * 8;
    L[0] = vx1; L[1] = vy1; L[2] = vx2; L[3] = vy2;
    L[4] = vobj; L[5] = vcc; L[6] = vcp; L[7] = 0.f;
    float offv = vcp * 4096.0f;
    x1o[j] = vx1 + offv; y1o[j] = vy1 + offv;
    x2o[j] = vx2 + offv; y2o[j] = vy2 + offv;
    area[j] = (x2o[j] - x1o[j]) * (y2o[j] - y1o[j]);
    key[j] = v ? ((((unsigned long long)flipKey(vsc)) << 25) |
                  (((unsigned long long)((0x7FFFu - vai) & 0x7FFFu)) << 10) |
                  (unsigned long long)c)
               : 0ull;
  }
  __syncthreads();

  const unsigned validThr = flipKey(NEGV * 0.5f);

  for (int it = 0; it < MAXDET; ++it) {
    unsigned long long lm = key[0];
    if (key[1] > lm) lm = key[1];
    if (key[2] > lm) lm = key[2];
    if (key[3] > lm) lm = key[3];
#pragma unroll
    for (int d = 32; d > 0; d >>= 1) {
      unsigned long long o2 = __shfl_xor(lm, d);
      if (o2 > lm) lm = o2;
    }
    if (lane == 0) swave[it & 1][wid] = lm;
    __syncthreads();
    unsigned long long best = swave[it & 1][0];
    if (swave[it & 1][1] > best) best = swave[it & 1][1];
    if (swave[it & 1][2] > best) best = swave[it & 1][2];
    if (swave[it & 1][3] > best) best = swave[it & 1][3];

    float* row = out + ((size_t)img * MAXDET + it) * 7;
    unsigned fk = (unsigned)(best >> 25);
    if (best == 0ull || fk <= validThr) {
      if (tid == 0) {
        row[0] = 0.f; row[1] = 0.f; row[2] = 0.f; row[3] = 0.f;
        row[4] = 0.f; row[5] = 0.f; row[6] = 0.f;
      }
      continue;  // uniform branch; remaining rows all zeros
    }
    int slot = (int)(best & 1023u);
    const float* L = lds + (size_t)slot * 8;
    float bx1 = L[0], by1 = L[1], bx2 = L[2], by2 = L[3];
    float bcp = L[6];
    float offb = bcp * 4096.0f;
    float bx1o = bx1 + offb, by1o = by1 + offb;
    float bx2o = bx2 + offb, by2o = by2 + offb;
    float areaB = (bx2o - bx1o) * (by2o - by1o);
    if (tid == (slot & 255)) {
      row[0] = bx1; row[1] = by1; row[2] = bx2; row[3] = by2;
      row[4] = L[4]; row[5] = L[5]; row[6] = bcp;
    }
#pragma unroll
    for (int j = 0; j < 4; ++j) {
      if (slot == j * 256 + tid) key[j] = 0ull;  // explicit clear (handles degenerate boxes)
      float lx = fmaxf(bx1o, x1o[j]), ly = fmaxf(by1o, y1o[j]);
      float rx = fminf(bx2o, x2o[j]), ry = fminf(by2o, y2o[j]);
      float iw = fmaxf(rx - lx, 0.f), ih = fmaxf(ry - ly, 0.f);
      float inter = iw * ih;
      float ua = areaB + area[j] - inter;
      float iou = (ua > 0.f) ? inter / ua : 0.f;  // IEEE div: bit-exact vs reference
      if (iou > 0.5f) key[j] = 0ull;
    }
  }
}

// ---------------- launch ----------------
extern "C" void kernel_launch(void* const* d_in, const int* in_sizes, int n_in,
                              void* d_out, int out_size, void* d_ws, size_t ws_size,
                              hipStream_t stream) {
  const float* regs = (const float*)d_in[0];
  const float* clses = (const float*)d_in[1];
  const float* anchors = (const float*)d_in[2];
  float* out = (float*)d_out;
  char* ws = (char*)d_ws;

  constexpr size_t HIST_BYTES = (size_t)BB * 65536 * 4;          // 4 MiB each
  constexpr size_t META_OFF = 2 * HIST_BYTES;
  constexpr size_t META_BYTES = 1024;
  constexpr size_t KEYS_OFF = META_OFF + META_BYTES;
  constexpr size_t ARR_BYTES = (size_t)BB * NN * 4;
  constexpr size_t CCS_OFF = KEYS_OFF + ARR_BYTES;
  constexpr size_t PREDS_OFF = CCS_OFF + ARR_BYTES;
  constexpr size_t CAND_OFF = PREDS_OFF + ARR_BYTES;
  constexpr size_t CAND_BYTES = (size_t)10 * BB * CAND_CAP * 4;
  constexpr size_t TIES_OFF = CAND_OFF + CAND_BYTES;

  unsigned* hist1 = (unsigned*)(ws);
  unsigned* hist2 = (unsigned*)(ws + HIST_BYTES);
  Meta* meta = (Meta*)(ws + META_OFF);
  unsigned* keys = (unsigned*)(ws + KEYS_OFF);
  float* ccs = (float*)(ws + CCS_OFF);
  int* preds = (int*)(ws + PREDS_OFF);
  float* cand = (float*)(ws + CAND_OFF);
  unsigned* ties = (unsigned*)(ws + TIES_OFF);

  // zero hist1 + hist2 + meta every launch (ws is not re-poisoned between replays)
  hipMemsetAsync(d_ws, 0, KEYS_OFF, stream);

  int blocks = (BB * NN + 255) / 256;
  k_score<<<blocks, 256, 0, stream>>>(regs, clses, keys, ccs, preds, hist1);
  k_scan<<<BB, 256, 0, stream>>>(hist1, meta, 1);
  k_hist2<<<blocks, 256, 0, stream>>>(keys, meta, hist2);
  k_scan<<<BB, 256, 0, stream>>>(hist2, meta, 2);
  k_compact<<<blocks, 256, 0, stream>>>(regs, anchors, keys, ccs, preds, meta, cand, ties);
  k_ties<<<BB, 256, 0, stream>>>(regs, anchors, ccs, preds, meta, ties, cand);
  k_nms<<<BB, 256, 0, stream>>>(cand, meta, out);
}